// Round 5
// baseline (892.943 us; speedup 1.0000x reference)
//
#include <hip/hip_runtime.h>
#include <cstdint>
#include <cstddef>

// Problem constants (B,H,W,C)=(4,128,128,512), HID=768, HEADS=8, BS=8
#define Bb     4
#define Cc     512
#define HID    768
#define HEADS  8
#define NBT    256
#define BS2    64
#define HD     96
#define HWTOK  16384
#define MTOK   65536
#define N3     2304

typedef __attribute__((ext_vector_type(8))) short frag16;
typedef __attribute__((ext_vector_type(4))) float f32x4;

__device__ __forceinline__ float b2f(unsigned short u) {
    union { unsigned int i; float f; } x; x.i = ((unsigned int)u) << 16; return x.f;
}
__device__ __forceinline__ unsigned short f2b(float f) {
    union { float f; unsigned int i; } x; x.f = f;
    unsigned int r = x.i + 0x7fffu + ((x.i >> 16) & 1u);   // RNE
    return (unsigned short)(r >> 16);
}
union cvt8 { uint4 u; unsigned short s[8]; };

__device__ __forceinline__ void gl2lds16(const void* g, void* l) {
    __builtin_amdgcn_global_load_lds(
        (const __attribute__((address_space(1))) unsigned int*)g,
        (__attribute__((address_space(3))) unsigned int*)l, 16, 0, 0);
}

// overflow-safe fast tanh: tanh(x) = sign(x) * (1-e)/(1+e), e = exp(-2|x|)
__device__ __forceinline__ float fast_tanh(float x) {
    float a = __builtin_fabsf(x);
    float t = __expf(-2.0f * a);
    float r = (1.0f - t) / (1.0f + t);
    return __builtin_copysignf(r, x);
}

// ---------------- kernel 0: weight transpose fp32 -> bf16 (B^T) ------------
__global__ __launch_bounds__(256) void k_transpose(
    const float* __restrict__ w, unsigned short* __restrict__ wt,
    int K, int N) {
    int e = blockIdx.x * 256 + threadIdx.x;
    if (e < K * N) {
        int k = e / N, n = e - k * N;
        wt[(size_t)n * K + k] = f2b(w[e]);
    }
}

// ---------------- kernel 0b: gather + fp32->bf16 convert of x --------------
__global__ __launch_bounds__(256) void k_gather(
    const float* __restrict__ x, const int* __restrict__ idx,
    unsigned short* __restrict__ xg) {          // (MTOK, 512) bf16
    int gid = blockIdx.x * 256 + threadIdx.x;   // MTOK*64 chunks of 8
    int t = gid >> 6, col = (gid & 63) * 8;
    int bb = t >> 14, hw = t & 16383;
    const float* src = x + ((size_t)bb * HWTOK + idx[hw]) * Cc + col;
    float4 f0 = *(const float4*)src, f1 = *(const float4*)(src + 4);
    cvt8 c;
    c.s[0] = f2b(f0.x); c.s[1] = f2b(f0.y); c.s[2] = f2b(f0.z); c.s[3] = f2b(f0.w);
    c.s[4] = f2b(f1.x); c.s[5] = f2b(f1.y); c.s[6] = f2b(f1.z); c.s[7] = f2b(f1.w);
    *(uint4*)(xg + (size_t)t * Cc + col) = c.u;
}

// ---------------- kernel 1: in_proj + GLU --------------------------------
// 64m x (64n x 3 slices) tile, all-LDS fragment-major staging (conflict-
// free), 2-buffer distance-1 counted-vmcnt pipeline, race closed by a
// trailing barrier.  acc[3][2][2]=48 AGPR + launch_bounds(256,4) -> 4
// waves/SIMD (2x TLP vs the 128m version, which was register-capped).
__global__ __launch_bounds__(256, 4) void k_inproj(
    const unsigned short* __restrict__ xg,     // (MTOK, 512) bf16
    const unsigned short* __restrict__ winT,   // (2304, 512) bf16
    const float* __restrict__ b_in,            // (2304) fp32
    unsigned short* __restrict__ y_img,        // (MTOK, HID) bf16
    unsigned short* __restrict__ vt_blk) {     // (HEADS,B,NBT,BS2,HD) bf16
    // 2 buffers x (A 4 subtiles + B 12 subtiles) x 1KB = 32 KB
    __shared__ alignas(16) unsigned short smem[2][8192];
    const int tid = threadIdx.x;
    const int wv = tid >> 6, lane = tid & 63;
    const int wm = wv >> 1, wn = wv & 1;
    const int fr = lane & 15, q = lane >> 4;

    // XCD swizzle: all 12 column-blocks of one 64-row panel -> same XCD
    const int fb = blockIdx.x + 12 * blockIdx.y;        // 0..12287 = 8*1536
    const int sb = (fb & 7) * 1536 + (fb >> 3);
    const int n0 = (sb % 12) * 64;      // per-slice col base [0,768)
    const int m0 = (sb / 12) * 64;

    // 16 DMA chunks of 1024B (A:0-3, B:4-15), 4 per wave.
    // fragment-order source: lane loads (row = sub*16 + fr, k = q*8..q*8+7)
    const unsigned short* gsrc[4];
    int loff[4];
    #pragma unroll
    for (int ci = 0; ci < 4; ci++) {
        int c = wv * 4 + ci;
        if (c < 4) {
            gsrc[ci] = xg + (size_t)(m0 + c * 16 + fr) * Cc + q * 8;
            loff[ci] = c * 512;
        } else {
            int cb = c - 4, sl = cb >> 2;
            gsrc[ci] = winT + (size_t)(sl * HID + n0 + (cb & 3) * 16 + fr) * Cc + q * 8;
            loff[ci] = 2048 + cb * 512;
        }
    }

    f32x4 acc[3][2][2];
    #pragma unroll
    for (int sl = 0; sl < 3; sl++)
        #pragma unroll
        for (int nt = 0; nt < 2; nt++)
            #pragma unroll
            for (int mt = 0; mt < 2; mt++) acc[sl][nt][mt] = (f32x4){0.f,0.f,0.f,0.f};

    // prologue: tile 0 in flight
    #pragma unroll
    for (int ci = 0; ci < 4; ci++) gl2lds16(gsrc[ci], &smem[0][loff[ci]]);

    // main loop: issue t+1, wait own tile t (vmcnt(4) = t+1 still flying),
    // barrier, compute t, trailing barrier (closes the 2-buffer race:
    // issue(t+1) happens only after every wave's compute(t-1) on the same
    // buffer has finished).
    #pragma unroll
    for (int t = 0; t < 16; t++) {
        if (t < 15) {
            #pragma unroll
            for (int ci = 0; ci < 4; ci++)
                gl2lds16(gsrc[ci] + (t + 1) * 32, &smem[(t + 1) & 1][loff[ci]]);
            asm volatile("s_waitcnt vmcnt(4)" ::: "memory");
        } else {
            asm volatile("s_waitcnt vmcnt(0)" ::: "memory");
        }
        __builtin_amdgcn_s_barrier();
        const unsigned short* sa = smem[t & 1];
        frag16 af[2];
        #pragma unroll
        for (int mt = 0; mt < 2; mt++)
            af[mt] = *(const frag16*)(sa + (wm * 2 + mt) * 512 + lane * 8);
        __builtin_amdgcn_s_setprio(1);
        #pragma unroll
        for (int sl = 0; sl < 3; sl++) {
            #pragma unroll
            for (int nt = 0; nt < 2; nt++) {
                frag16 bf = *(const frag16*)(sa + 2048 +
                                             (sl * 4 + wn * 2 + nt) * 512 + lane * 8);
                #pragma unroll
                for (int mt = 0; mt < 2; mt++)
                    acc[sl][nt][mt] = __builtin_amdgcn_mfma_f32_16x16x32_bf16(
                        af[mt], bf, acc[sl][nt][mt], 0, 0, 0);
            }
        }
        __builtin_amdgcn_s_setprio(0);
        if (t < 15) __builtin_amdgcn_s_barrier();
    }

    // epilogue: GLU + layout writes
    #pragma unroll
    for (int nt = 0; nt < 2; nt++) {
        const int j = n0 + wn * 32 + nt * 16 + fr;
        const float bs = b_in[j], bv = b_in[HID + j], by = b_in[2 * HID + j];
        const int h = j / HD, d = j - h * HD;
        #pragma unroll
        for (int mt = 0; mt < 2; mt++) {
            #pragma unroll
            for (int r = 0; r < 4; r++) {
                const int t = m0 + wm * 32 + mt * 16 + q * 4 + r;
                const int bb = t >> 14, hw = t & 16383;
                const float sv = acc[0][nt][mt][r] + bs;
                const float vv = acc[1][nt][mt][r] + bv;
                const float yv = acc[2][nt][mt][r] + by;
                y_img[(size_t)t * HID + j] = f2b(yv);
                const int hr = hw >> 7, wc = hw & 127;
                const int nblk = ((hr >> 3) << 4) | (wc >> 3);
                const int ii   = ((hr & 7) << 3) | (wc & 7);
                vt_blk[((((size_t)h * Bb + bb) * NBT + nblk) * BS2 + ii) * HD + d] =
                    f2b(vv * fast_tanh(sv));
            }
        }
    }
}

// ---------------- kernel 2: block attention (MFMA) + y multiply ------------
// av[i,d] = sum_j attn[g,i,j] * vt[g,j,d];  y_img <- av * y_img (in place)
__global__ __launch_bounds__(256) void k_attn(
    const float* __restrict__ attnw,            // (HEADS,B,NBT,64,64) fp32
    const unsigned short* __restrict__ vt_blk,  // (HEADS,B,NBT,64,96) bf16
    unsigned short* __restrict__ y_img) {       // (MTOK,HID) bf16, in/out
    __shared__ alignas(16) unsigned short Aat[64][72];   // attn bf16, padded
    __shared__ alignas(16) unsigned short VtT[96][72];   // vt transposed (B^T)
    const int tid = threadIdx.x;
    const int g = blockIdx.x;                   // (h*B + b)*NBT + n
    const int wv = tid >> 6, lane = tid & 63;
    const int fr = lane & 15, q = lane >> 4;
    const int wm = wv >> 1, wn = wv & 1;

    const float* asrc = attnw + (size_t)g * 4096;
    const unsigned short* vsrc = vt_blk + (size_t)g * 6144;
    #pragma unroll
    for (int r = 0; r < 2; r++) {               // attn: 512 chunks of 8 floats
        int v = tid + 256 * r;
        int i = v >> 3, jj = (v & 7) * 8;
        const float* ap = asrc + (size_t)v * 8;
        float4 f0 = *(const float4*)ap, f1 = *(const float4*)(ap + 4);
        cvt8 c;
        c.s[0]=f2b(f0.x); c.s[1]=f2b(f0.y); c.s[2]=f2b(f0.z); c.s[3]=f2b(f0.w);
        c.s[4]=f2b(f1.x); c.s[5]=f2b(f1.y); c.s[6]=f2b(f1.z); c.s[7]=f2b(f1.w);
        *(uint4*)(&Aat[i][jj]) = c.u;
    }
    #pragma unroll
    for (int r = 0; r < 3; r++) {               // vt: 768 uint4, transpose
        int v = tid + 256 * r;
        int j = v / 12, dq = v - j * 12;
        cvt8 c; c.u = ((const uint4*)vsrc)[v];
        #pragma unroll
        for (int e = 0; e < 8; e++) VtT[dq * 8 + e][j] = c.s[e];
    }
    __syncthreads();

    f32x4 acc[2][3];                            // [mt:i][ndt:d]
    #pragma unroll
    for (int mt = 0; mt < 2; mt++)
        #pragma unroll
        for (int nd = 0; nd < 3; nd++) acc[mt][nd] = (f32x4){0.f,0.f,0.f,0.f};
    #pragma unroll
    for (int kk = 0; kk < 2; kk++) {
        frag16 af[2];
        #pragma unroll
        for (int mt = 0; mt < 2; mt++)
            af[mt] = *(const frag16*)(&Aat[wm * 32 + mt * 16 + fr][kk * 32 + q * 8]);
        #pragma unroll
        for (int nd = 0; nd < 3; nd++) {
            frag16 bf = *(const frag16*)(&VtT[wn * 48 + nd * 16 + fr][kk * 32 + q * 8]);
            #pragma unroll
            for (int mt = 0; mt < 2; mt++)
                acc[mt][nd] = __builtin_amdgcn_mfma_f32_16x16x32_bf16(
                    af[mt], bf, acc[mt][nd], 0, 0, 0);
        }
    }

    const int h = g >> 10, b = (g >> 8) & 3, n = g & 255;
    #pragma unroll
    for (int nd = 0; nd < 3; nd++) {
        const int d = wn * 48 + nd * 16 + fr;
        #pragma unroll
        for (int mt = 0; mt < 2; mt++) {
            #pragma unroll
            for (int r = 0; r < 4; r++) {
                const int i = wm * 32 + mt * 16 + q * 4 + r;
                const int hr = ((n >> 4) << 3) | (i >> 3);
                const int wc = ((n & 15) << 3) | (i & 7);
                const size_t t = ((size_t)b << 14) + (size_t)hr * 128 + wc;
                const size_t off = t * HID + (size_t)h * HD + d;
                y_img[off] = f2b(acc[mt][nd][r] * b2f(y_img[off]));
            }
        }
    }
}

// ---------------- kernel 3: out_proj + bias + scatter ----------------------
// 64m x 128c tile, same 2-buffer counted-vmcnt + trailing-barrier pipeline.
// acc[4][2]=32 AGPR + launch_bounds(256,4) -> 4 waves/SIMD.
__global__ __launch_bounds__(256, 4) void k_outproj(
    const unsigned short* __restrict__ avy,     // (MTOK,HID) bf16 (=y_img)
    const unsigned short* __restrict__ woutT,   // (512, 768) bf16
    const float* __restrict__ b_out,            // (512) fp32
    const int* __restrict__ idx,
    float* __restrict__ out) {                  // (B,HW,C) fp32
    // 2 buffers x (A 4 subtiles + B 8 subtiles) x 1KB = 24 KB
    __shared__ alignas(16) unsigned short smem[2][6144];
    const int tid = threadIdx.x;
    const int wv = tid >> 6, lane = tid & 63;
    const int wm = wv >> 1, wn = wv & 1;
    const int fr = lane & 15, q = lane >> 4;

    const int fb = blockIdx.x + 4 * blockIdx.y;         // 0..4095 = 8*512
    const int sb = (fb & 7) * 512 + (fb >> 3);
    const int c0 = (sb % 4) * 128;
    const int m0 = (sb / 4) * 64;

    // 12 DMA chunks of 1024B (A:0-3, B:4-11), 3 per wave
    const unsigned short* gsrc[3];
    int loff[3];
    #pragma unroll
    for (int ci = 0; ci < 3; ci++) {
        int c = wv * 3 + ci;
        if (c < 4) {
            gsrc[ci] = avy + (size_t)(m0 + c * 16 + fr) * HID + q * 8;
            loff[ci] = c * 512;
        } else {
            int cb = c - 4;
            gsrc[ci] = woutT + (size_t)(c0 + cb * 16 + fr) * HID + q * 8;
            loff[ci] = 2048 + cb * 512;
        }
    }

    f32x4 acc[4][2];
    #pragma unroll
    for (int nt = 0; nt < 4; nt++)
        #pragma unroll
        for (int mt = 0; mt < 2; mt++) acc[nt][mt] = (f32x4){0.f,0.f,0.f,0.f};

    #pragma unroll
    for (int ci = 0; ci < 3; ci++) gl2lds16(gsrc[ci], &smem[0][loff[ci]]);

    #pragma unroll
    for (int t = 0; t < 24; t++) {
        if (t < 23) {
            #pragma unroll
            for (int ci = 0; ci < 3; ci++)
                gl2lds16(gsrc[ci] + (t + 1) * 32, &smem[(t + 1) & 1][loff[ci]]);
            asm volatile("s_waitcnt vmcnt(3)" ::: "memory");
        } else {
            asm volatile("s_waitcnt vmcnt(0)" ::: "memory");
        }
        __builtin_amdgcn_s_barrier();
        const unsigned short* sa = smem[t & 1];
        frag16 af[2];
        #pragma unroll
        for (int mt = 0; mt < 2; mt++)
            af[mt] = *(const frag16*)(sa + (wm * 2 + mt) * 512 + lane * 8);
        __builtin_amdgcn_s_setprio(1);
        #pragma unroll
        for (int nt = 0; nt < 4; nt++) {
            frag16 bf = *(const frag16*)(sa + 2048 + (wn * 4 + nt) * 512 + lane * 8);
            #pragma unroll
            for (int mt = 0; mt < 2; mt++)
                acc[nt][mt] = __builtin_amdgcn_mfma_f32_16x16x32_bf16(
                    af[mt], bf, acc[nt][mt], 0, 0, 0);
        }
        __builtin_amdgcn_s_setprio(0);
        if (t < 23) __builtin_amdgcn_s_barrier();
    }

    #pragma unroll
    for (int nt = 0; nt < 4; nt++) {
        const int c = c0 + wn * 64 + nt * 16 + fr;
        const float bo = b_out[c];
        #pragma unroll
        for (int mt = 0; mt < 2; mt++) {
            #pragma unroll
            for (int r = 0; r < 4; r++) {
                const int t = m0 + wm * 32 + mt * 16 + q * 4 + r;
                const int bb = t >> 14, hw = t & 16383;
                const int dst = idx[hw];
                out[((size_t)bb * HWTOK + dst) * Cc + c] = acc[nt][mt][r] + bo;
            }
        }
    }
}

extern "C" void kernel_launch(void* const* d_in, const int* in_sizes, int n_in,
                              void* d_out, int out_size, void* d_ws, size_t ws_size,
                              hipStream_t stream) {
    const float* x     = (const float*)d_in[0];
    const float* attnw = (const float*)d_in[1];
    const float* W_in  = (const float*)d_in[2];
    const float* b_in  = (const float*)d_in[3];
    const float* W_out = (const float*)d_in[4];
    const float* b_out = (const float*)d_in[5];
    const int*   idx   = (const int*)d_in[6];
    float*       out   = (float*)d_out;

    // workspace carve-up (~204.5 MB)
    char* p = (char*)d_ws;
    unsigned short* winT  = (unsigned short*)p; p += (size_t)N3 * Cc * 2;
    unsigned short* woutT = (unsigned short*)p; p += (size_t)Cc * HID * 2;
    unsigned short* vt    = (unsigned short*)p; p += (size_t)HEADS * Bb * NBT * BS2 * HD * 2;
    unsigned short* y_img = (unsigned short*)p; p += (size_t)MTOK * HID * 2;
    // xg (67 MB bf16) lives in d_out — dead until k_outproj writes it
    unsigned short* xg = (unsigned short*)d_out;

    k_transpose<<<(N3 * Cc + 255) / 256, 256, 0, stream>>>(W_in, winT, Cc, N3);
    k_transpose<<<(HID * Cc + 255) / 256, 256, 0, stream>>>(W_out, woutT, HID, Cc);
    k_gather<<<MTOK * 64 / 256, 256, 0, stream>>>(x, idx, xg);

    dim3 g1(HID / 64, MTOK / 64);   // (12, 1024)
    k_inproj<<<g1, 256, 0, stream>>>(xg, winT, b_in, y_img, vt);

    k_attn<<<HEADS * Bb * NBT, 256, 0, stream>>>(attnw, vt, y_img);

    dim3 g3(Cc / 128, MTOK / 64);   // (4, 1024)
    k_outproj<<<g3, 256, 0, stream>>>(y_img, woutT, b_out, idx, out);
}

// Round 6
// 723.169 us; speedup vs baseline: 1.2348x; 1.2348x over previous
//
#include <hip/hip_runtime.h>
#include <cstdint>
#include <cstddef>

// Problem constants (B,H,W,C)=(4,128,128,512), HID=768, HEADS=8, BS=8
#define Bb     4
#define Cc     512
#define HID    768
#define HEADS  8
#define NBT    256
#define BS2    64
#define HD     96
#define HWTOK  16384
#define MTOK   65536
#define N3     2304
// stride of one head plane in block layout (shorts)
#define HSTR   ((size_t)Bb * NBT * BS2 * HD)

typedef __attribute__((ext_vector_type(8))) short frag16;
typedef __attribute__((ext_vector_type(4))) float f32x4;

__device__ __forceinline__ float b2f(unsigned short u) {
    union { unsigned int i; float f; } x; x.i = ((unsigned int)u) << 16; return x.f;
}
__device__ __forceinline__ unsigned short f2b(float f) {
    union { float f; unsigned int i; } x; x.f = f;
    unsigned int r = x.i + 0x7fffu + ((x.i >> 16) & 1u);   // RNE
    return (unsigned short)(r >> 16);
}
union cvt8 { uint4 u; unsigned short s[8]; };

__device__ __forceinline__ void gl2lds16(const void* g, void* l) {
    __builtin_amdgcn_global_load_lds(
        (const __attribute__((address_space(1))) unsigned int*)g,
        (__attribute__((address_space(3))) unsigned int*)l, 16, 0, 0);
}

// overflow-safe fast tanh: tanh(x) = sign(x) * (1-e)/(1+e), e = exp(-2|x|)
__device__ __forceinline__ float fast_tanh(float x) {
    float a = __builtin_fabsf(x);
    float t = __expf(-2.0f * a);
    float r = (1.0f - t) / (1.0f + t);
    return __builtin_copysignf(r, x);
}

// block-layout K-offset for outproj A reads: K index k0 -> head h, col d0
__device__ __forceinline__ size_t aoff(int kt) {
    const int k0 = kt * 32;
    return (size_t)(k0 / HD) * HSTR + (size_t)(k0 % HD);
}

// ---------------- kernel 0: weight transpose fp32 -> bf16 (B^T) ------------
__global__ __launch_bounds__(256) void k_transpose(
    const float* __restrict__ w, unsigned short* __restrict__ wt,
    int K, int N) {
    int e = blockIdx.x * 256 + threadIdx.x;
    if (e < K * N) {
        int k = e / N, n = e - k * N;
        wt[(size_t)n * K + k] = f2b(w[e]);
    }
}

// ---------------- kernel 0b: gather + fp32->bf16 convert of x --------------
__global__ __launch_bounds__(256) void k_gather(
    const float* __restrict__ x, const int* __restrict__ idx,
    unsigned short* __restrict__ xg) {          // (MTOK, 512) bf16
    int gid = blockIdx.x * 256 + threadIdx.x;   // MTOK*64 chunks of 8
    int t = gid >> 6, col = (gid & 63) * 8;
    int bb = t >> 14, hw = t & 16383;
    const float* src = x + ((size_t)bb * HWTOK + idx[hw]) * Cc + col;
    float4 f0 = *(const float4*)src, f1 = *(const float4*)(src + 4);
    cvt8 c;
    c.s[0] = f2b(f0.x); c.s[1] = f2b(f0.y); c.s[2] = f2b(f0.z); c.s[3] = f2b(f0.w);
    c.s[4] = f2b(f1.x); c.s[5] = f2b(f1.y); c.s[6] = f2b(f1.z); c.s[7] = f2b(f1.w);
    *(uint4*)(xg + (size_t)t * Cc + col) = c.u;
}

// ---------------- kernel 1: in_proj + GLU --------------------------------
// R3 structure (best measured: 278 us): 128m x (64n x 3 slices) tile,
// fragment-major LDS (conflict-free), distance-1 counted-vmcnt pipeline,
// now 3 LDS buffers (closes the 2-buffer laggard race with ONE barrier).
// Both v (GLU) and y are written in BLOCK layout at the SAME address.
__global__ __launch_bounds__(256) void k_inproj(
    const unsigned short* __restrict__ xg,     // (MTOK, 512) bf16
    const unsigned short* __restrict__ winT,   // (2304, 512) bf16
    const float* __restrict__ b_in,            // (2304) fp32
    unsigned short* __restrict__ y_blk,        // (HEADS,B,NBT,BS2,HD) bf16
    unsigned short* __restrict__ vt_blk) {     // (HEADS,B,NBT,BS2,HD) bf16
    // 3 buffers x (A 8 subtiles + B 12 subtiles) x 1KB = 60 KB
    __shared__ alignas(16) unsigned short smem[3][10240];
    const int tid = threadIdx.x;
    const int wv = tid >> 6, lane = tid & 63;
    const int wm = wv >> 1, wn = wv & 1;
    const int fr = lane & 15, q = lane >> 4;

    // XCD swizzle: all 12 column-blocks of one 128-row panel -> same XCD
    const int fb = blockIdx.x + 12 * blockIdx.y;        // 0..6143 = 8*768
    const int sb = (fb & 7) * 768 + (fb >> 3);
    const int n0 = (sb % 12) * 64;      // per-slice col base [0,768)
    const int m0 = (sb / 12) * 128;

    // 20 DMA chunks of 1024B (A:0-7, B:8-19), 5 per wave.
    const unsigned short* gsrc[5];
    int loff[5];
    #pragma unroll
    for (int ci = 0; ci < 5; ci++) {
        int c = wv * 5 + ci;
        if (c < 8) {
            gsrc[ci] = xg + (size_t)(m0 + c * 16 + fr) * Cc + q * 8;
            loff[ci] = c * 512;
        } else {
            int cb = c - 8, sl = cb >> 2;
            gsrc[ci] = winT + (size_t)(sl * HID + n0 + (cb & 3) * 16 + fr) * Cc + q * 8;
            loff[ci] = 4096 + cb * 512;
        }
    }

    f32x4 acc[3][2][4];
    #pragma unroll
    for (int sl = 0; sl < 3; sl++)
        #pragma unroll
        for (int nt = 0; nt < 2; nt++)
            #pragma unroll
            for (int mt = 0; mt < 4; mt++) acc[sl][nt][mt] = (f32x4){0.f,0.f,0.f,0.f};

    // prologue: tile 0 in flight
    #pragma unroll
    for (int ci = 0; ci < 5; ci++) gl2lds16(gsrc[ci], &smem[0][loff[ci]]);

    // issue t+1 -> buf (t+1)%3, wait own tile t (vmcnt(5)), barrier, compute.
    #pragma unroll
    for (int t = 0; t < 16; t++) {
        if (t < 15) {
            #pragma unroll
            for (int ci = 0; ci < 5; ci++)
                gl2lds16(gsrc[ci] + (t + 1) * 32, &smem[(t + 1) % 3][loff[ci]]);
            asm volatile("s_waitcnt vmcnt(5)" ::: "memory");
        } else {
            asm volatile("s_waitcnt vmcnt(0)" ::: "memory");
        }
        __builtin_amdgcn_s_barrier();
        const unsigned short* sa = smem[t % 3];
        frag16 af[4];
        #pragma unroll
        for (int mt = 0; mt < 4; mt++)
            af[mt] = *(const frag16*)(sa + (wm * 4 + mt) * 512 + lane * 8);
        __builtin_amdgcn_s_setprio(1);
        #pragma unroll
        for (int sl = 0; sl < 3; sl++) {
            #pragma unroll
            for (int nt = 0; nt < 2; nt++) {
                frag16 bf = *(const frag16*)(sa + 4096 +
                                             (sl * 4 + wn * 2 + nt) * 512 + lane * 8);
                #pragma unroll
                for (int mt = 0; mt < 4; mt++)
                    acc[sl][nt][mt] = __builtin_amdgcn_mfma_f32_16x16x32_bf16(
                        af[mt], bf, acc[sl][nt][mt], 0, 0, 0);
            }
        }
        __builtin_amdgcn_s_setprio(0);
    }

    // epilogue: GLU + block-layout writes (one shared address for v and y)
    #pragma unroll
    for (int nt = 0; nt < 2; nt++) {
        const int j = n0 + wn * 32 + nt * 16 + fr;
        const float bs = b_in[j], bv = b_in[HID + j], by = b_in[2 * HID + j];
        const int h = j / HD, d = j - h * HD;
        #pragma unroll
        for (int mt = 0; mt < 4; mt++) {
            #pragma unroll
            for (int r = 0; r < 4; r++) {
                const int t = m0 + wm * 64 + mt * 16 + q * 4 + r;
                const int bb = t >> 14, hw = t & 16383;
                const float sv = acc[0][nt][mt][r] + bs;
                const float vv = acc[1][nt][mt][r] + bv;
                const float yv = acc[2][nt][mt][r] + by;
                const int hr = hw >> 7, wc = hw & 127;
                const int nblk = ((hr >> 3) << 4) | (wc >> 3);
                const int ii   = ((hr & 7) << 3) | (wc & 7);
                const size_t boff =
                    ((((size_t)h * Bb + bb) * NBT + nblk) * BS2 + ii) * HD + d;
                y_blk[boff]  = f2b(yv);
                vt_blk[boff] = f2b(vv * fast_tanh(sv));
            }
        }
    }
}

// ---------------- kernel 2: block attention (MFMA) + y multiply ------------
// av[i,d] = sum_j attn[g,i,j] * vt[g,j,d];  y_blk[g] <- av * y_blk[g]
// y now lives in block layout: staged to LDS by DMA (contiguous 12 KB),
// multiplied from LDS, written back in place -- no scattered global RMW.
__global__ __launch_bounds__(256) void k_attn(
    const float* __restrict__ attnw,            // (HEADS,B,NBT,64,64) fp32
    const unsigned short* __restrict__ vt_blk,  // (HEADS,B,NBT,64,96) bf16
    unsigned short* y_blk) {                    // (HEADS,B,NBT,64,96) bf16 io
    __shared__ alignas(16) unsigned short Aat[64][72];   // attn bf16, padded
    __shared__ alignas(16) unsigned short VtT[96][72];   // vt transposed (B^T)
    __shared__ alignas(16) unsigned short Yt[64 * 96];   // y tile, row-major
    const int tid = threadIdx.x;
    const int g = blockIdx.x;                   // (h*B + b)*NBT + n
    const int wv = tid >> 6, lane = tid & 63;
    const int fr = lane & 15, q = lane >> 4;
    const int wm = wv >> 1, wn = wv & 1;

    const float* asrc = attnw + (size_t)g * 4096;
    const unsigned short* vsrc = vt_blk + (size_t)g * 6144;
    unsigned short* ysrc = y_blk + (size_t)g * 6144;

    // y tile -> LDS via DMA (3 x 1KB per wave), overlaps the conversions
    #pragma unroll
    for (int r = 0; r < 3; r++) {
        const int vb = wv * 64 + r * 256;                // wave-uniform
        gl2lds16(ysrc + (size_t)(vb + lane) * 8, Yt + (size_t)vb * 8);
    }
    #pragma unroll
    for (int r = 0; r < 2; r++) {               // attn: 512 chunks of 8 floats
        int v = tid + 256 * r;
        int i = v >> 3, jj = (v & 7) * 8;
        const float* ap = asrc + (size_t)v * 8;
        float4 f0 = *(const float4*)ap, f1 = *(const float4*)(ap + 4);
        cvt8 c;
        c.s[0]=f2b(f0.x); c.s[1]=f2b(f0.y); c.s[2]=f2b(f0.z); c.s[3]=f2b(f0.w);
        c.s[4]=f2b(f1.x); c.s[5]=f2b(f1.y); c.s[6]=f2b(f1.z); c.s[7]=f2b(f1.w);
        *(uint4*)(&Aat[i][jj]) = c.u;
    }
    #pragma unroll
    for (int r = 0; r < 3; r++) {               // vt: 768 uint4, transpose
        int v = tid + 256 * r;
        int j = v / 12, dq = v - j * 12;
        cvt8 c; c.u = ((const uint4*)vsrc)[v];
        #pragma unroll
        for (int e = 0; e < 8; e++) VtT[dq * 8 + e][j] = c.s[e];
    }
    __syncthreads();   // drains vmcnt (Yt DMA) + lgkmcnt

    f32x4 acc[2][3];                            // [mt:i][ndt:d]
    #pragma unroll
    for (int mt = 0; mt < 2; mt++)
        #pragma unroll
        for (int nd = 0; nd < 3; nd++) acc[mt][nd] = (f32x4){0.f,0.f,0.f,0.f};
    #pragma unroll
    for (int kk = 0; kk < 2; kk++) {
        frag16 af[2];
        #pragma unroll
        for (int mt = 0; mt < 2; mt++)
            af[mt] = *(const frag16*)(&Aat[wm * 32 + mt * 16 + fr][kk * 32 + q * 8]);
        #pragma unroll
        for (int nd = 0; nd < 3; nd++) {
            frag16 bf = *(const frag16*)(&VtT[wn * 48 + nd * 16 + fr][kk * 32 + q * 8]);
            #pragma unroll
            for (int mt = 0; mt < 2; mt++)
                acc[mt][nd] = __builtin_amdgcn_mfma_f32_16x16x32_bf16(
                    af[mt], bf, acc[mt][nd], 0, 0, 0);
        }
    }

    // epilogue: av * y from LDS, write back in place (block-local region)
    #pragma unroll
    for (int nd = 0; nd < 3; nd++) {
        const int d = wn * 48 + nd * 16 + fr;
        #pragma unroll
        for (int mt = 0; mt < 2; mt++) {
            #pragma unroll
            for (int r = 0; r < 4; r++) {
                const int i = wm * 32 + mt * 16 + q * 4 + r;
                const float yv = b2f(Yt[i * HD + d]);
                ysrc[i * HD + d] = f2b(acc[mt][nd][r] * yv);
            }
        }
    }
}

// ---------------- kernel 3: out_proj + bias + scatter ----------------------
// R3 structure (128m x 128c, distance-1 counted vmcnt), 3 LDS buffers.
// A (avy) is read from BLOCK layout via per-lane DMA sources: waves 0-1
// stage A (per-K-step offset aoff(t) = h*HSTR + d0), waves 2-3 stage B.
__global__ __launch_bounds__(256) void k_outproj(
    const unsigned short* __restrict__ avy,     // (HEADS,B,NBT,64,96) bf16
    const unsigned short* __restrict__ woutT,   // (512, 768) bf16
    const float* __restrict__ b_out,            // (512) fp32
    const int* __restrict__ idx,
    float* __restrict__ out) {                  // (B,HW,C) fp32
    // 3 buffers x (A 8 + B 8 subtiles) x 1KB = 48 KB
    __shared__ alignas(16) unsigned short smem[3][8192];
    const int tid = threadIdx.x;
    const int wv = tid >> 6, lane = tid & 63;
    const int wm = wv >> 1, wn = wv & 1;
    const int fr = lane & 15, q = lane >> 4;

    const int fb = blockIdx.x + 4 * blockIdx.y;         // 0..2047 = 8*256
    const int sb = (fb & 7) * 256 + (fb >> 3);
    const int c0 = (sb % 4) * 128;
    const int m0 = (sb / 4) * 128;

    const unsigned short* gsrc[4];
    int loff[4];
    #pragma unroll
    for (int ci = 0; ci < 4; ci++) {
        int c = wv * 4 + ci;
        if (c < 8) {                            // A: token row -> block layout
            int tok = m0 + c * 16 + fr;
            int bb = tok >> 14, hw = tok & 16383;
            int hr = hw >> 7, wc = hw & 127;
            int nblk = ((hr >> 3) << 4) | (wc >> 3);
            int ii = ((hr & 7) << 3) | (wc & 7);
            gsrc[ci] = avy + (((size_t)bb * NBT + nblk) * BS2 + ii) * HD + q * 8;
            loff[ci] = c * 512;
        } else {
            int cb = c - 8;
            gsrc[ci] = woutT + (size_t)(c0 + cb * 16 + fr) * HID + q * 8;
            loff[ci] = 4096 + cb * 512;
        }
    }
    const bool waveA = (wv < 2);

    f32x4 acc[4][4];
    #pragma unroll
    for (int nt = 0; nt < 4; nt++)
        #pragma unroll
        for (int mt = 0; mt < 4; mt++) acc[nt][mt] = (f32x4){0.f,0.f,0.f,0.f};

    #pragma unroll
    for (int ci = 0; ci < 4; ci++) gl2lds16(gsrc[ci], &smem[0][loff[ci]]);

    #pragma unroll
    for (int t = 0; t < 24; t++) {
        if (t < 23) {
            const size_t off = waveA ? aoff(t + 1) : (size_t)(t + 1) * 32;
            #pragma unroll
            for (int ci = 0; ci < 4; ci++)
                gl2lds16(gsrc[ci] + off, &smem[(t + 1) % 3][loff[ci]]);
            asm volatile("s_waitcnt vmcnt(4)" ::: "memory");
        } else {
            asm volatile("s_waitcnt vmcnt(0)" ::: "memory");
        }
        __builtin_amdgcn_s_barrier();
        const unsigned short* sa = smem[t % 3];
        frag16 af[4];
        #pragma unroll
        for (int mt = 0; mt < 4; mt++)
            af[mt] = *(const frag16*)(sa + (wm * 4 + mt) * 512 + lane * 8);
        __builtin_amdgcn_s_setprio(1);
        #pragma unroll
        for (int nt = 0; nt < 4; nt++) {
            frag16 bf = *(const frag16*)(sa + 4096 +
                                         (wn * 4 + nt) * 512 + lane * 8);
            #pragma unroll
            for (int mt = 0; mt < 4; mt++)
                acc[nt][mt] = __builtin_amdgcn_mfma_f32_16x16x32_bf16(
                    af[mt], bf, acc[nt][mt], 0, 0, 0);
        }
        __builtin_amdgcn_s_setprio(0);
    }

    #pragma unroll
    for (int nt = 0; nt < 4; nt++) {
        const int c = c0 + wn * 64 + nt * 16 + fr;
        const float bo = b_out[c];
        #pragma unroll
        for (int mt = 0; mt < 4; mt++) {
            #pragma unroll
            for (int r = 0; r < 4; r++) {
                const int t = m0 + wm * 64 + mt * 16 + q * 4 + r;
                const int bb = t >> 14, hw = t & 16383;
                const int dst = idx[hw];
                out[((size_t)bb * HWTOK + dst) * Cc + c] = acc[nt][mt][r] + bo;
            }
        }
    }
}

extern "C" void kernel_launch(void* const* d_in, const int* in_sizes, int n_in,
                              void* d_out, int out_size, void* d_ws, size_t ws_size,
                              hipStream_t stream) {
    const float* x     = (const float*)d_in[0];
    const float* attnw = (const float*)d_in[1];
    const float* W_in  = (const float*)d_in[2];
    const float* b_in  = (const float*)d_in[3];
    const float* W_out = (const float*)d_in[4];
    const float* b_out = (const float*)d_in[5];
    const int*   idx   = (const int*)d_in[6];
    float*       out   = (float*)d_out;

    // workspace carve-up (~204.5 MB)
    char* p = (char*)d_ws;
    unsigned short* winT  = (unsigned short*)p; p += (size_t)N3 * Cc * 2;
    unsigned short* woutT = (unsigned short*)p; p += (size_t)Cc * HID * 2;
    unsigned short* vt    = (unsigned short*)p; p += (size_t)HEADS * Bb * NBT * BS2 * HD * 2;
    unsigned short* y_blk = (unsigned short*)p; p += (size_t)HEADS * Bb * NBT * BS2 * HD * 2;
    // xg (67 MB bf16) lives in d_out — dead until k_outproj writes it
    unsigned short* xg = (unsigned short*)d_out;

    k_transpose<<<(N3 * Cc + 255) / 256, 256, 0, stream>>>(W_in, winT, Cc, N3);
    k_transpose<<<(HID * Cc + 255) / 256, 256, 0, stream>>>(W_out, woutT, HID, Cc);
    k_gather<<<MTOK * 64 / 256, 256, 0, stream>>>(x, idx, xg);

    dim3 g1(HID / 64, MTOK / 128);  // (12, 512)
    k_inproj<<<g1, 256, 0, stream>>>(xg, winT, b_in, y_blk, vt);

    k_attn<<<HEADS * Bb * NBT, 256, 0, stream>>>(attnw, vt, y_blk);

    dim3 g3(Cc / 128, MTOK / 128);  // (4, 512)
    k_outproj<<<g3, 256, 0, stream>>>(y_blk, woutT, b_out, idx, out);
}